// Round 2
// baseline (448.158 us; speedup 1.0000x reference)
//
#include <hip/hip_runtime.h>

typedef __attribute__((ext_vector_type(2)))  __fp16   pk16x2;  // cvt_pkrtz result type
typedef __attribute__((ext_vector_type(4)))  float    f32x4;
typedef __attribute__((ext_vector_type(16))) float    f32x16;
typedef __attribute__((ext_vector_type(8)))  _Float16 f16x8;

#define NB 2
#define NN 384
#define NO 4
#define NC 128
#define NK 64
#define MROWS 8             // m rows per block (MFMA rows = 4 o x 8 m)
#define NSPLIT 16
#define NS (NN / NSPLIT)    // 24 source points per block
#define DEPTH 4
#define SLOTF 2048          // floats per A slot (8 rows x 256 floats = 8 KB)
#define SLOTB 8192

union F16x8u { f16x8 v; pk16x2 h[4]; };

__device__ __forceinline__ void async16(const float* g, float* l) {
    __builtin_amdgcn_global_load_lds((const __attribute__((address_space(1))) void*)g,
                                     (__attribute__((address_space(3))) void*)l, 16, 0, 0);
}

// ---------------------------------------------------------------------------
// Stage 1 (R2 restructure): block = (b, 8-row m-tile, n-split); ALL 4 o.
// MFMA row index = o*8 + m_local. Per n the A-tile is KB[m0..7][n][o][k] =
// 8 x 1024 B FULLY CONTIGUOUS rows (1 global_load_lds instr = 1 row), and
// consecutive n are contiguous -> ideal DRAM streaming. B-frag = Ws only
// (no per-n B rebuild); x applied post-MFMA in f32:
//   acc[r] += x[n, o(r)] * D[r],  D = sum_k KB_f16[m,n,o,k] * Ws_f16[k,c]
// Chunk rotation R(m)=2m+(m>>2) on load source + matching read offsets makes
// ds_read_b128 bank residues perfectly uniform (conflict-free).
// vmcnt ladder: 2 loads/stage, 3 stages in flight, wait vmcnt<=4 at loop top.
// ---------------------------------------------------------------------------
__global__ __launch_bounds__(256, 3)
void sepconv_stage1(const float* __restrict__ KB, const float* __restrict__ X,
                    const float* __restrict__ Ws, float* __restrict__ part)
{
    extern __shared__ float smem[];
    float* Abuf = smem;                  // DEPTH * 2048 floats (32 KB)

    const int t    = threadIdx.x;
    const int lane = t & 63;
    const int w    = t >> 6;
    const int l31  = lane & 31;
    const int lh   = lane >> 5;

    const int bid   = blockIdx.x;
    const int mt    = bid % 48;
    const int b     = (bid / 48) & 1;
    const int split = bid / 96;
    const int n0    = split * NS;
    const int cidx  = w * 32 + l31;

    // Ws -> f16 B-fragment registers (this wave's c-subtile); k = kc*16+lh*8+j
    f16x8 wsreg[4];
    {
        const float* wp = Ws + (lh * 8) * NC + cidx;
#pragma unroll
        for (int kc = 0; kc < 4; ++kc) {
            f16x8 v;
#pragma unroll
            for (int j = 0; j < 8; ++j)
                v[j] = (_Float16)wp[(kc * 16 + j) * NC];
            wsreg[kc] = v;
        }
    }

    // x slice -> registers: xr[i] = { x[b,n0+i,o,cidx] : o=0..3 } as 2 packed f16.
    pk16x2 xr[NS][2];
#pragma unroll
    for (int i = 0; i < NS; ++i) {
        const float* xp = X + ((size_t)(b * NN + n0 + i) * NO) * NC + cidx;
        pk16x2 h0, h1;
        h0[0] = (_Float16)xp[0];
        h0[1] = (_Float16)xp[NC];
        h1[0] = (_Float16)xp[2 * NC];
        h1[1] = (_Float16)xp[3 * NC];
        xr[i][0] = h0; xr[i][1] = h1;
    }

    // A staging pointers: instr j stages the FULL contiguous 1 KB row (2w+j),
    // with 16 B chunks rotated by R(row) (source-side half of the swizzle).
    const float* gb[2];
#pragma unroll
    for (int j = 0; j < 2; ++j) {
        const int row = 2 * w + j;
        const int m   = mt * MROWS + row;
        const int R   = 2 * row + (row >> 2);
        gb[j] = KB + ((size_t)(b * NN + m) * NN + n0) * (NO * NK)
                   + (((lane + R) & 63) << 2);
    }

    // frag-read byte offsets within a slot (rotation-aware, conflict-free):
    // A row a = l31 -> (o = a>>3, m = a&7); k = kc*16 + lh*8 + j.
    const int mloc = l31 & 7;
    const int ol   = l31 >> 3;
    const int Rm   = 2 * mloc + (mloc >> 2);
    int apos[4][2];
#pragma unroll
    for (int kc = 0; kc < 4; ++kc)
#pragma unroll
        for (int e = 0; e < 2; ++e) {
            const int g = ol * 16 + kc * 4 + lh * 2 + e;   // logical 16B chunk
            apos[kc][e] = mloc * 1024 + (((g - Rm) & 63) << 4);
        }

    f32x16 acc, zero16;
#pragma unroll
    for (int r = 0; r < 16; ++r) { acc[r] = 0.f; zero16[r] = 0.f; }

    auto stage = [&](int nl, int slot) {
        float* lb = Abuf + slot * SLOTF;
#pragma unroll
        for (int j = 0; j < 2; ++j)
            async16(gb[j] + nl * (NO * NK), lb + (2 * w + j) * 256);
    };

    auto compute = [&](int i, int slot) {
        const char* sb = (const char*)Abuf + slot * SLOTB;
        f32x16 D;
#pragma unroll
        for (int kc = 0; kc < 4; ++kc) {
            const f32x4 a0 = *(const f32x4*)(sb + apos[kc][0]);
            const f32x4 a1 = *(const f32x4*)(sb + apos[kc][1]);
            F16x8u af;
            af.h[0] = __builtin_amdgcn_cvt_pkrtz(a0[0], a0[1]);
            af.h[1] = __builtin_amdgcn_cvt_pkrtz(a0[2], a0[3]);
            af.h[2] = __builtin_amdgcn_cvt_pkrtz(a1[0], a1[1]);
            af.h[3] = __builtin_amdgcn_cvt_pkrtz(a1[2], a1[3]);
            D = __builtin_amdgcn_mfma_f32_32x32x16_f16(af.v, wsreg[kc],
                                                       kc == 0 ? zero16 : D, 0, 0, 0);
        }
        // post-MFMA x scale: output row of D[r] = (r&3)+8*(r>>2)+4*lh -> o = r>>2
        const float xsv[4] = { (float)xr[i][0][0], (float)xr[i][0][1],
                               (float)xr[i][1][0], (float)xr[i][1][1] };
#pragma unroll
        for (int r = 0; r < 16; ++r)
            acc[r] += xsv[r >> 2] * D[r];
    };

    __builtin_amdgcn_sched_barrier(0);    // x/Ws loads+converts drained before stage(0)
    stage(0, 0);
    stage(1, 1);
    stage(2, 2);
    __builtin_amdgcn_sched_barrier(0);

    // Steady state: outstanding = stages {i, i+1, i+2} = 6 loads at loop top;
    // vmcnt<=4 retires stage(i); barrier publishes it; issue stage(i+3) into
    // the slot compute(i-1) finished with before this barrier.
#pragma unroll
    for (int i = 0; i < NS - 3; ++i) {
        __builtin_amdgcn_s_waitcnt(0x0F74);   // vmcnt<=4
        __builtin_amdgcn_s_barrier();         // raw: no vmcnt(0) drain
        __builtin_amdgcn_sched_barrier(0);
        stage(i + 3, (i + 3) & 3);
        __builtin_amdgcn_sched_barrier(0);
        compute(i, i & 3);
    }
    // tail: i = NS-3, NS-2, NS-1 (no more stages; drain 4 -> 2 -> 0)
    __builtin_amdgcn_s_waitcnt(0x0F74); __builtin_amdgcn_s_barrier();
    __builtin_amdgcn_sched_barrier(0);
    compute(NS - 3, (NS - 3) & 3);
    __builtin_amdgcn_s_waitcnt(0x0F72); __builtin_amdgcn_s_barrier();
    __builtin_amdgcn_sched_barrier(0);
    compute(NS - 2, (NS - 2) & 3);
    __builtin_amdgcn_s_waitcnt(0x0F70); __builtin_amdgcn_s_barrier();
    __builtin_amdgcn_sched_barrier(0);
    compute(NS - 1, (NS - 1) & 3);

    // epilogue: fp32 partials [split][b][o][m][c]; D row -> (o = r>>2, ml = (r&3)+4*lh)
    float* pb = part + ((size_t)(split * NB + b) * NO) * (NN * NC)
                     + (size_t)(mt * MROWS) * NC + cidx;
#pragma unroll
    for (int r = 0; r < 16; ++r) {
        const int o  = r >> 2;
        const int ml = (r & 3) + 4 * lh;
        pb[(size_t)o * (NN * NC) + (size_t)ml * NC] = acc[r];
    }
}

// ---------------------------------------------------------------------------
// Stage 2: reduce splits, fiber/rot mixing + bias (unchanged — part layout
// identical, isolates the stage1 restructure).
// ---------------------------------------------------------------------------
__global__ __launch_bounds__(256)
void sepconv_stage2(const float* __restrict__ part, const float* __restrict__ fiber,
                    const float* __restrict__ Wr, const float* __restrict__ bias,
                    float* __restrict__ out, int nsplit)
{
    const int bid = blockIdx.x;
    const int b = bid / NN;
    const int m = bid % NN;
    const int t = threadIdx.x;
    const int c = t & 127;
    const int g = t >> 7;

    float rot[8];
#pragma unroll
    for (int i = 0; i < 8; ++i) rot[i] = 0.f;
    for (int k = 0; k < NK; ++k) {
        const float wv = Wr[k * NC + c];
#pragma unroll
        for (int q = 0; q < 2; ++q)
#pragma unroll
            for (int oo = 0; oo < 4; ++oo)
                rot[q * 4 + oo] += fiber[((2 * g + q) * NO + oo) * NK + k] * wv;
    }

    float y1[4];
#pragma unroll
    for (int oo = 0; oo < 4; ++oo) {
        float s = 0.f;
        for (int sp = 0; sp < nsplit; ++sp)
            s += part[((size_t)(sp * NB + b) * NO + oo) * (NN * NC) + m * NC + c];
        y1[oo] = s;
    }

    const float bv = bias[c];
#pragma unroll
    for (int q = 0; q < 2; ++q) {
        float v = bv;
#pragma unroll
        for (int oo = 0; oo < 4; ++oo) v += y1[oo] * rot[q * 4 + oo];
        out[((b * NN + m) * NO + (2 * g + q)) * NC + c] = v;
    }
}

extern "C" void kernel_launch(void* const* d_in, const int* in_sizes, int n_in,
                              void* d_out, int out_size, void* d_ws, size_t ws_size,
                              hipStream_t stream)
{
    const float* X    = (const float*)d_in[0];
    const float* KB   = (const float*)d_in[1];
    const float* FB   = (const float*)d_in[2];
    const float* Ws   = (const float*)d_in[3];
    const float* Wr   = (const float*)d_in[4];
    const float* bias = (const float*)d_in[5];
    float* out  = (float*)d_out;
    float* part = (float*)d_ws;   // 16 * 1.57 MB = 25 MB of fp32 partials

    const size_t lds = (size_t)DEPTH * SLOTF * sizeof(float);  // 32768 B

    sepconv_stage1<<<dim3(48 * NB * NSPLIT), dim3(256), lds, stream>>>(KB, X, Ws, part);
    sepconv_stage2<<<dim3(NB * NN), dim3(256), 0, stream>>>(part, FB, Wr, bias, out, NSPLIT);
}

// Round 3
// 447.100 us; speedup vs baseline: 1.0024x; 1.0024x over previous
//
#include <hip/hip_runtime.h>

typedef __attribute__((ext_vector_type(2)))  __fp16   pk16x2;  // cvt_pkrtz result type
typedef __attribute__((ext_vector_type(4)))  float    f32x4;
typedef __attribute__((ext_vector_type(16))) float    f32x16;
typedef __attribute__((ext_vector_type(8)))  _Float16 f16x8;

#define NB 2
#define NN 384
#define NO 4
#define NC 128
#define NK 64
#define MROWS 8             // m rows per block (MFMA rows = 4 o x 8 m)
#define NSPLIT 16
#define NS (NN / NSPLIT)    // 24 source points per block
#define NPH (NS / 2)        // 12 phases, 2 source points per phase
#define DEPTH 3
#define SLOTF 4096          // floats per A slot (2 n x 8 rows x 256 floats = 16 KB)
#define SLOTB 16384
#define HSLOTB 8192         // bytes per n-subslot

union F16x8u { f16x8 v; pk16x2 h[4]; };

__device__ __forceinline__ void async16(const float* g, float* l) {
    __builtin_amdgcn_global_load_lds((const __attribute__((address_space(1))) void*)g,
                                     (__attribute__((address_space(3))) void*)l, 16, 0, 0);
}

// ---------------------------------------------------------------------------
// Stage 1 (R3): same math/layout as R2, but 2 source points per pipeline phase.
//   12 barrier rounds instead of 24; 16 KB staged per phase (4 instr/wave);
//   8 MFMA + 16 ds_read_b128 between barriers; 32 KB/block in flight.
// MFMA row index = o*8 + m_local; A-tile rows KB[m][n][o][k] contiguous 1 KB,
// staged 1 row per global_load_lds. B-frag = Ws only; x applied post-MFMA in
// f32. Chunk rotation R(m)=2m+(m>>2) keeps ds_read_b128 conflict-free.
// ---------------------------------------------------------------------------
__global__ __launch_bounds__(256, 3)
void sepconv_stage1(const float* __restrict__ KB, const float* __restrict__ X,
                    const float* __restrict__ Ws, float* __restrict__ part)
{
    extern __shared__ float smem[];
    float* Abuf = smem;                  // DEPTH * 4096 floats (48 KB)

    const int t    = threadIdx.x;
    const int lane = t & 63;
    const int w    = t >> 6;
    const int l31  = lane & 31;
    const int lh   = lane >> 5;

    const int bid   = blockIdx.x;
    const int mt    = bid % 48;
    const int b     = (bid / 48) & 1;
    const int split = bid / 96;
    const int n0    = split * NS;
    const int cidx  = w * 32 + l31;

    // Ws -> f16 B-fragment registers (this wave's c-subtile); k = kc*16+lh*8+j
    f16x8 wsreg[4];
    {
        const float* wp = Ws + (lh * 8) * NC + cidx;
#pragma unroll
        for (int kc = 0; kc < 4; ++kc) {
            f16x8 v;
#pragma unroll
            for (int j = 0; j < 8; ++j)
                v[j] = (_Float16)wp[(kc * 16 + j) * NC];
            wsreg[kc] = v;
        }
    }

    // x slice -> registers: xr[i] = { x[b,n0+i,o,cidx] : o=0..3 } as 2 packed f16.
    pk16x2 xr[NS][2];
#pragma unroll
    for (int i = 0; i < NS; ++i) {
        const float* xp = X + ((size_t)(b * NN + n0 + i) * NO) * NC + cidx;
        pk16x2 h0, h1;
        h0[0] = (_Float16)xp[0];
        h0[1] = (_Float16)xp[NC];
        h1[0] = (_Float16)xp[2 * NC];
        h1[1] = (_Float16)xp[3 * NC];
        xr[i][0] = h0; xr[i][1] = h1;
    }

    // A staging pointers: wave w owns m-rows {2w, 2w+1}; 16 B chunks rotated
    // by R(row) on the source side (half of the bank swizzle).
    const float* gb[2];
#pragma unroll
    for (int j = 0; j < 2; ++j) {
        const int row = 2 * w + j;
        const int m   = mt * MROWS + row;
        const int R   = 2 * row + (row >> 2);
        gb[j] = KB + ((size_t)(b * NN + m) * NN + n0) * (NO * NK)
                   + (((lane + R) & 63) << 2);
    }

    // frag-read byte offsets within an n-subslot (rotation-aware, conflict-free):
    // A row a = l31 -> (o = a>>3, m = a&7); k = kc*16 + lh*8 + j.
    const int mloc = l31 & 7;
    const int ol   = l31 >> 3;
    const int Rm   = 2 * mloc + (mloc >> 2);
    int apos[4][2];
#pragma unroll
    for (int kc = 0; kc < 4; ++kc)
#pragma unroll
        for (int e = 0; e < 2; ++e) {
            const int g = ol * 16 + kc * 4 + lh * 2 + e;   // logical 16B chunk
            apos[kc][e] = mloc * 1024 + (((g - Rm) & 63) << 4);
        }

    f32x16 acc, zero16;
#pragma unroll
    for (int r = 0; r < 16; ++r) { acc[r] = 0.f; zero16[r] = 0.f; }

    // stage phase ph: 2 n (2ph, 2ph+1) x 2 m-rows = 4 instrs/wave, 16 KB/block
    auto stage = [&](int ph, int slot) {
        float* lb = Abuf + slot * SLOTF;
#pragma unroll
        for (int nn = 0; nn < 2; ++nn)
#pragma unroll
            for (int j = 0; j < 2; ++j)
                async16(gb[j] + (2 * ph + nn) * (NO * NK),
                        lb + nn * 2048 + (2 * w + j) * 256);
    };

    auto computeOne = [&](int i, const char* sbn) {
        f32x16 D;
#pragma unroll
        for (int kc = 0; kc < 4; ++kc) {
            const f32x4 a0 = *(const f32x4*)(sbn + apos[kc][0]);
            const f32x4 a1 = *(const f32x4*)(sbn + apos[kc][1]);
            F16x8u af;
            af.h[0] = __builtin_amdgcn_cvt_pkrtz(a0[0], a0[1]);
            af.h[1] = __builtin_amdgcn_cvt_pkrtz(a0[2], a0[3]);
            af.h[2] = __builtin_amdgcn_cvt_pkrtz(a1[0], a1[1]);
            af.h[3] = __builtin_amdgcn_cvt_pkrtz(a1[2], a1[3]);
            D = __builtin_amdgcn_mfma_f32_32x32x16_f16(af.v, wsreg[kc],
                                                       kc == 0 ? zero16 : D, 0, 0, 0);
        }
        // post-MFMA x scale: output row of D[r] -> o = r>>2
        const float xsv[4] = { (float)xr[i][0][0], (float)xr[i][0][1],
                               (float)xr[i][1][0], (float)xr[i][1][1] };
#pragma unroll
        for (int r = 0; r < 16; ++r)
            acc[r] += xsv[r >> 2] * D[r];
    };

    auto computePair = [&](int ph, int slot) {
        const char* sb = (const char*)Abuf + slot * SLOTB;
        computeOne(2 * ph,     sb);
        computeOne(2 * ph + 1, sb + HSLOTB);
    };

    __builtin_amdgcn_sched_barrier(0);    // x/Ws loads+converts drained before stage(0)
    stage(0, 0);
    stage(1, 1);
    __builtin_amdgcn_sched_barrier(0);

    // At top of phase ph: outstanding = stage(ph) [4] + stage(ph+1) [4].
    // vmcnt<=4 retires stage(ph); barrier publishes it; stage(ph+2) reuses the
    // slot compute(ph-1) finished with (all waves past it via this barrier).
#pragma unroll
    for (int ph = 0; ph < NPH - 2; ++ph) {
        __builtin_amdgcn_s_waitcnt(0x0F74);   // vmcnt<=4
        __builtin_amdgcn_s_barrier();         // raw: no vmcnt(0) drain
        __builtin_amdgcn_sched_barrier(0);
        stage(ph + 2, (ph + 2) % DEPTH);
        __builtin_amdgcn_sched_barrier(0);
        computePair(ph, ph % DEPTH);
    }
    // tail: ph = NPH-2, NPH-1 (no more stages; drain 4 -> 0)
    __builtin_amdgcn_s_waitcnt(0x0F74); __builtin_amdgcn_s_barrier();
    __builtin_amdgcn_sched_barrier(0);
    computePair(NPH - 2, (NPH - 2) % DEPTH);
    __builtin_amdgcn_s_waitcnt(0x0F70); __builtin_amdgcn_s_barrier();
    __builtin_amdgcn_sched_barrier(0);
    computePair(NPH - 1, (NPH - 1) % DEPTH);

    // epilogue: fp32 partials [split][b][o][m][c]; D row -> (o = r>>2, ml = (r&3)+4*lh)
    float* pb = part + ((size_t)(split * NB + b) * NO) * (NN * NC)
                     + (size_t)(mt * MROWS) * NC + cidx;
#pragma unroll
    for (int r = 0; r < 16; ++r) {
        const int o  = r >> 2;
        const int ml = (r & 3) + 4 * lh;
        pb[(size_t)o * (NN * NC) + (size_t)ml * NC] = acc[r];
    }
}

// ---------------------------------------------------------------------------
// Stage 2: reduce splits, fiber/rot mixing + bias (unchanged — part layout
// identical, isolates the stage1 phase-granularity experiment).
// ---------------------------------------------------------------------------
__global__ __launch_bounds__(256)
void sepconv_stage2(const float* __restrict__ part, const float* __restrict__ fiber,
                    const float* __restrict__ Wr, const float* __restrict__ bias,
                    float* __restrict__ out, int nsplit)
{
    const int bid = blockIdx.x;
    const int b = bid / NN;
    const int m = bid % NN;
    const int t = threadIdx.x;
    const int c = t & 127;
    const int g = t >> 7;

    float rot[8];
#pragma unroll
    for (int i = 0; i < 8; ++i) rot[i] = 0.f;
    for (int k = 0; k < NK; ++k) {
        const float wv = Wr[k * NC + c];
#pragma unroll
        for (int q = 0; q < 2; ++q)
#pragma unroll
            for (int oo = 0; oo < 4; ++oo)
                rot[q * 4 + oo] += fiber[((2 * g + q) * NO + oo) * NK + k] * wv;
    }

    float y1[4];
#pragma unroll
    for (int oo = 0; oo < 4; ++oo) {
        float s = 0.f;
        for (int sp = 0; sp < nsplit; ++sp)
            s += part[((size_t)(sp * NB + b) * NO + oo) * (NN * NC) + m * NC + c];
        y1[oo] = s;
    }

    const float bv = bias[c];
#pragma unroll
    for (int q = 0; q < 2; ++q) {
        float v = bv;
#pragma unroll
        for (int oo = 0; oo < 4; ++oo) v += y1[oo] * rot[q * 4 + oo];
        out[((b * NN + m) * NO + (2 * g + q)) * NC + c] = v;
    }
}

extern "C" void kernel_launch(void* const* d_in, const int* in_sizes, int n_in,
                              void* d_out, int out_size, void* d_ws, size_t ws_size,
                              hipStream_t stream)
{
    const float* X    = (const float*)d_in[0];
    const float* KB   = (const float*)d_in[1];
    const float* FB   = (const float*)d_in[2];
    const float* Ws   = (const float*)d_in[3];
    const float* Wr   = (const float*)d_in[4];
    const float* bias = (const float*)d_in[5];
    float* out  = (float*)d_out;
    float* part = (float*)d_ws;   // 16 * 1.57 MB = 25 MB of fp32 partials

    const size_t lds = (size_t)DEPTH * SLOTF * sizeof(float);  // 49152 B

    sepconv_stage1<<<dim3(48 * NB * NSPLIT), dim3(256), lds, stream>>>(KB, X, Ws, part);
    sepconv_stage2<<<dim3(NB * NN), dim3(256), 0, stream>>>(part, FB, Wr, bias, out, NSPLIT);
}